// Round 9
// baseline (101.888 us; speedup 1.0000x reference)
//
#include <hip/hip_runtime.h>
#include <math.h>

#define N 4096
#define D 128
#define NT 32                 // 4096/128 tiles per dim
#define NBLK (NT*(NT+1)/2)    // 528 tiles, one block each
#define BIGV 1e30f

typedef __bf16 bf16x8 __attribute__((ext_vector_type(8)));
typedef float  f32x4  __attribute__((ext_vector_type(4)));

// ---- device-scope (LLC coherence point) accessors ----
__device__ __forceinline__ void stg(float* p, float v) {
  __hip_atomic_store(p, v, __ATOMIC_RELAXED, __HIP_MEMORY_SCOPE_AGENT);
}
__device__ __forceinline__ void stg8(void* p, unsigned long long v) {
  __hip_atomic_store((unsigned long long*)p, v, __ATOMIC_RELAXED, __HIP_MEMORY_SCOPE_AGENT);
}
__device__ __forceinline__ float ldg1(const float* p) {
  return __hip_atomic_load((float*)p, __ATOMIC_RELAXED, __HIP_MEMORY_SCOPE_AGENT);
}
__device__ __forceinline__ unsigned ldu(const unsigned* p) {
  return __hip_atomic_load((unsigned*)p, __ATOMIC_RELAXED, __HIP_MEMORY_SCOPE_AGENT);
}
// 16-byte MFMA fragment via two 8-byte device-scope loads (compiler-tracked waits)
__device__ __forceinline__ bf16x8 ldfrag(const ushort* p) {
  unsigned long long a = __hip_atomic_load((const unsigned long long*)p,
                                           __ATOMIC_RELAXED, __HIP_MEMORY_SCOPE_AGENT);
  unsigned long long b = __hip_atomic_load((const unsigned long long*)(p + 4),
                                           __ATOMIC_RELAXED, __HIP_MEMORY_SCOPE_AGENT);
  union { unsigned long long q[2]; bf16x8 v; } u;
  u.q[0] = a; u.q[1] = b;
  return u.v;
}

// ---- monotone IEEE-754 <-> uint key (bijective; atomicMin/Max == float min/max) ----
__device__ __forceinline__ unsigned enc(float f) {
  unsigned u = __float_as_uint(f);
  return (u & 0x80000000u) ? ~u : (u | 0x80000000u);
}
__device__ __forceinline__ float dec(unsigned k) {
  unsigned u = (k & 0x80000000u) ? (k & 0x7FFFFFFFu) : ~k;
  return __uint_as_float(u);
}

// ---- flag-based device barrier over NBLK blocks (no RMW storm) ----
__device__ __forceinline__ void post_flag(unsigned* flags, unsigned ep, int tid, int bid) {
  __syncthreads();
  if (tid == 0) {
    asm volatile("s_waitcnt vmcnt(0)" ::: "memory");
    __hip_atomic_store(&flags[bid], ep, __ATOMIC_RELAXED, __HIP_MEMORY_SCOPE_AGENT);
  }
}
__device__ __forceinline__ bool flags_ready(const unsigned* flags, unsigned ep, int tid) {
  unsigned a0 = ldu(&flags[tid]);
  unsigned a1 = ldu(&flags[tid + 256]);
  bool ok = (a0 >= ep) && (a1 >= ep);
  if (tid < NBLK - 512) ok = ok && (ldu(&flags[tid + 512]) >= ep);
  return ok;
}
__device__ __forceinline__ void gbar(unsigned* flags, unsigned* rel,
                                     unsigned ep, int tid, int bid) {
  post_flag(flags, ep, tid, bid);
  if (bid == 0) {
    while (!flags_ready(flags, ep, tid)) __builtin_amdgcn_s_sleep(2);
    __syncthreads();
    if (tid == 0)
      __hip_atomic_store(rel, ep, __ATOMIC_RELAXED, __HIP_MEMORY_SCOPE_AGENT);
  }
  if (tid == 0) {
    while (ldu(rel) < ep) __builtin_amdgcn_s_sleep(4);
  }
  asm volatile("" ::: "memory");
  __syncthreads();
}

__device__ __forceinline__ ushort bf16_rne(float f) {
  unsigned u = __float_as_uint(f);
  unsigned r = u + 0x7FFFu + ((u >> 16) & 1u);
  return (ushort)(r >> 16);
}

__device__ __forceinline__ void epi_minmax_I(const f32x4 (&acc)[4][4],
    const int* tgI, const int* tgJ, float* redA, float* redB,
    unsigned* __restrict__ minE, unsigned* __restrict__ maxE, int i0, int tid)
{
  const int l = tid & 63, wid = tid >> 6;
  const int wr = wid >> 1, wc = wid & 1;
  const int g = l >> 4, c = l & 15;
  int tgc[4];
#pragma unroll
  for (int n = 0; n < 4; ++n) tgc[n] = tgJ[wc * 64 + n * 16 + c];
  __syncthreads();
#pragma unroll
  for (int m = 0; m < 4; ++m)
#pragma unroll
    for (int jj = 0; jj < 4; ++jj) {
      int row_loc = wr * 64 + m * 16 + g * 4 + jj;
      int trow = tgI[row_loc];
      float mn = BIGV, mx = -BIGV;
#pragma unroll
      for (int n = 0; n < 4; ++n) {
        float s = acc[m][n][jj];
        if (trow == tgc[n]) { if (s < 1.0f) mn = fminf(mn, s); }
        else                  mx = fmaxf(mx, s);
      }
#pragma unroll
      for (int msk = 1; msk < 16; msk <<= 1) {
        mn = fminf(mn, __shfl_xor(mn, msk, 64));
        mx = fmaxf(mx, __shfl_xor(mx, msk, 64));
      }
      if (c == 0) { redA[wc * 128 + row_loc] = mn; redB[wc * 128 + row_loc] = mx; }
    }
  __syncthreads();
  if (tid < 128) {
    float mn = fminf(redA[tid], redA[128 + tid]);
    float mx = fmaxf(redB[tid], redB[128 + tid]);
    if (mn <  BIGV) atomicMin(&minE[i0 + tid], enc(mn));
    if (mx > -BIGV) atomicMax(&maxE[i0 + tid], enc(mx));
  }
}

__device__ __forceinline__ void epi_minmax_J(const f32x4 (&acc)[4][4],
    const int* tgI, const int* tgJ, float* redA, float* redB,
    unsigned* __restrict__ minE, unsigned* __restrict__ maxE, int j0, int tid)
{
  const int l = tid & 63, wid = tid >> 6;
  const int wr = wid >> 1, wc = wid & 1;
  const int g = l >> 4, c = l & 15;
  int tgc[4];
#pragma unroll
  for (int n = 0; n < 4; ++n) tgc[n] = tgJ[wc * 64 + n * 16 + c];
  __syncthreads();
  float mnn[4], mxx[4];
#pragma unroll
  for (int n = 0; n < 4; ++n) { mnn[n] = BIGV; mxx[n] = -BIGV; }
#pragma unroll
  for (int m = 0; m < 4; ++m)
#pragma unroll
    for (int jj = 0; jj < 4; ++jj) {
      int row_loc = wr * 64 + m * 16 + g * 4 + jj;
      int tcol = tgI[row_loc];
#pragma unroll
      for (int n = 0; n < 4; ++n) {
        float s = acc[m][n][jj];
        if (tgc[n] == tcol) { if (s < 1.0f) mnn[n] = fminf(mnn[n], s); }
        else                  mxx[n] = fmaxf(mxx[n], s);
      }
    }
#pragma unroll
  for (int n = 0; n < 4; ++n) {
#pragma unroll
    for (int msk = 16; msk < 64; msk <<= 1) {
      mnn[n] = fminf(mnn[n], __shfl_xor(mnn[n], msk, 64));
      mxx[n] = fmaxf(mxx[n], __shfl_xor(mxx[n], msk, 64));
    }
  }
  if (g == 0) {
#pragma unroll
    for (int n = 0; n < 4; ++n) {
      redA[wr * 128 + wc * 64 + n * 16 + c] = mnn[n];
      redB[wr * 128 + wc * 64 + n * 16 + c] = mxx[n];
    }
  }
  __syncthreads();
  if (tid < 128) {
    float mn = fminf(redA[tid], redA[128 + tid]);
    float mx = fmaxf(redB[tid], redB[128 + tid]);
    if (mn <  BIGV) atomicMin(&minE[j0 + tid], enc(mn));
    if (mx > -BIGV) atomicMax(&maxE[j0 + tid], enc(mx));
  }
}

__device__ __forceinline__ void epi_mine_I(const f32x4 (&acc)[4][4],
    const int* tgI, const int* tgJ,
    const float* rd0, const float* rd1, const float* rd2, const float* rd3,
    float* redA, float* redB, float* redC, float* redD,
    float* __restrict__ possum, float* __restrict__ negsum,
    float* __restrict__ apsum,  float* __restrict__ ansum,
    int i0, int mode, int tid)
{
  const int l = tid & 63, wid = tid >> 6;
  const int wr = wid >> 1, wc = wid & 1;
  const int g = l >> 4, c = l & 15;
  int tgc[4];
#pragma unroll
  for (int n = 0; n < 4; ++n) tgc[n] = tgJ[wc * 64 + n * 16 + c];
  __syncthreads();
#pragma unroll
  for (int m = 0; m < 4; ++m)
#pragma unroll
    for (int jj = 0; jj < 4; ++jj) {
      int row_loc = wr * 64 + m * 16 + g * 4 + jj;
      int trow = tgI[row_loc];
      float mnp = rd0[row_loc], mxn = rd1[row_loc];
      float mg  = rd2[row_loc], wt  = rd3[row_loc];
      float ps = 0.f, ns = 0.f, apv = 0.f, anv = 0.f;
#pragma unroll
      for (int n = 0; n < 4; ++n) {
        float s = acc[m][n][jj];
        bool same = (trow == tgc[n]);
        if (mode == 1) {
          float wsim = s * wt;
          if (same) {
            if (s < 1.0f && (mxn - s + mg > 0.f)) { ps += __expf(-2.f * (wsim - 0.5f)); apv += 1.f; }
          } else {
            if (s + mg - mnp > 0.f) { ns += __expf(10.f * (wsim - 0.5f)); anv += 1.f; }
          }
        } else {
          if (same) {
            if (s < 1.0f) { ps += __expf(-2.f * (s - 0.5f - mg)); apv += 1.f; }
          } else {
            ns += __expf(10.f * (s - 0.5f + mg)); anv += 1.f;
          }
        }
      }
#pragma unroll
      for (int msk = 1; msk < 16; msk <<= 1) {
        ps  += __shfl_xor(ps,  msk, 64);
        ns  += __shfl_xor(ns,  msk, 64);
        apv += __shfl_xor(apv, msk, 64);
        anv += __shfl_xor(anv, msk, 64);
      }
      if (c == 0) {
        redA[wc * 128 + row_loc] = ps;  redB[wc * 128 + row_loc] = ns;
        redC[wc * 128 + row_loc] = apv; redD[wc * 128 + row_loc] = anv;
      }
    }
  __syncthreads();
  if (tid < 128) {
    float v;
    v = redA[tid] + redA[128 + tid]; if (v != 0.f) atomicAdd(&possum[i0 + tid], v);
    v = redB[tid] + redB[128 + tid]; if (v != 0.f) atomicAdd(&negsum[i0 + tid], v);
    v = redC[tid] + redC[128 + tid]; if (v != 0.f) atomicAdd(&apsum[i0 + tid], v);
    v = redD[tid] + redD[128 + tid]; if (v != 0.f) atomicAdd(&ansum[i0 + tid], v);
  }
}

__device__ __forceinline__ void epi_mine_J(const f32x4 (&acc)[4][4],
    const int* tgI, const int* tgJ,
    const float* rd0, const float* rd1, const float* rd2, const float* rd3,
    float* redA, float* redB, float* redC, float* redD,
    float* __restrict__ possum, float* __restrict__ negsum,
    float* __restrict__ apsum,  float* __restrict__ ansum,
    int j0, int mode, int tid)
{
  const int l = tid & 63, wid = tid >> 6;
  const int wr = wid >> 1, wc = wid & 1;
  const int g = l >> 4, c = l & 15;
  int tgc[4];
#pragma unroll
  for (int n = 0; n < 4; ++n) tgc[n] = tgJ[wc * 64 + n * 16 + c];
  __syncthreads();
  float mnpJ[4], mxnJ[4], mgJ[4], wtJ[4];
#pragma unroll
  for (int n = 0; n < 4; ++n) {
    int jr = wc * 64 + n * 16 + c;
    mnpJ[n] = rd0[jr]; mxnJ[n] = rd1[jr]; mgJ[n] = rd2[jr]; wtJ[n] = rd3[jr];
  }
  float psn[4], nsn[4], apn[4], ann[4];
#pragma unroll
  for (int n = 0; n < 4; ++n) { psn[n] = 0.f; nsn[n] = 0.f; apn[n] = 0.f; ann[n] = 0.f; }
#pragma unroll
  for (int m = 0; m < 4; ++m)
#pragma unroll
    for (int jj = 0; jj < 4; ++jj) {
      int row_loc = wr * 64 + m * 16 + g * 4 + jj;
      int tcol = tgI[row_loc];
#pragma unroll
      for (int n = 0; n < 4; ++n) {
        float s = acc[m][n][jj];
        bool same = (tgc[n] == tcol);
        if (mode == 1) {
          float wsim = s * wtJ[n];
          if (same) {
            if (s < 1.0f && (mxnJ[n] - s + mgJ[n] > 0.f)) { psn[n] += __expf(-2.f * (wsim - 0.5f)); apn[n] += 1.f; }
          } else {
            if (s + mgJ[n] - mnpJ[n] > 0.f) { nsn[n] += __expf(10.f * (wsim - 0.5f)); ann[n] += 1.f; }
          }
        } else {
          if (same) {
            if (s < 1.0f) { psn[n] += __expf(-2.f * (s - 0.5f - mgJ[n])); apn[n] += 1.f; }
          } else {
            nsn[n] += __expf(10.f * (s - 0.5f + mgJ[n])); ann[n] += 1.f;
          }
        }
      }
    }
#pragma unroll
  for (int n = 0; n < 4; ++n) {
#pragma unroll
    for (int msk = 16; msk < 64; msk <<= 1) {
      psn[n] += __shfl_xor(psn[n], msk, 64);
      nsn[n] += __shfl_xor(nsn[n], msk, 64);
      apn[n] += __shfl_xor(apn[n], msk, 64);
      ann[n] += __shfl_xor(ann[n], msk, 64);
    }
  }
  if (g == 0) {
#pragma unroll
    for (int n = 0; n < 4; ++n) {
      int col_loc = wc * 64 + n * 16 + c;
      redA[wr * 128 + col_loc] = psn[n]; redB[wr * 128 + col_loc] = nsn[n];
      redC[wr * 128 + col_loc] = apn[n]; redD[wr * 128 + col_loc] = ann[n];
    }
  }
  __syncthreads();
  if (tid < 128) {
    float v;
    v = redA[tid] + redA[128 + tid]; if (v != 0.f) atomicAdd(&possum[j0 + tid], v);
    v = redB[tid] + redB[128 + tid]; if (v != 0.f) atomicAdd(&negsum[j0 + tid], v);
    v = redC[tid] + redC[128 + tid]; if (v != 0.f) atomicAdd(&apsum[j0 + tid], v);
    v = redD[tid] + redD[128 + tid]; if (v != 0.f) atomicAdd(&ansum[j0 + tid], v);
  }
}

__global__ __launch_bounds__(256, 3)
void k_fused(const float* __restrict__ x, const int* __restrict__ tgt,
             const float* __restrict__ marg, const float* __restrict__ wgt,
             const int* __restrict__ hm, float* __restrict__ out,
             ushort* __restrict__ xh, ushort* __restrict__ xl,
             unsigned* __restrict__ minE, unsigned* __restrict__ maxE,
             float* __restrict__ possum, float* __restrict__ negsum,
             float* __restrict__ apsum,  float* __restrict__ ansum,
             float* __restrict__ lpart, unsigned* flags, unsigned* rel,
             unsigned* done)
{
  __shared__ int tgI[128], tgJ[128];
  __shared__ float rdI0[128], rdI1[128], rdI2[128], rdI3[128];
  __shared__ float rdJ0[128], rdJ1[128], rdJ2[128], rdJ3[128];
  __shared__ float redA[256], redB[256], redC[256], redD[256];

  const int tid = threadIdx.x;
  const int bid = blockIdx.x;

  // ---- Phase 0: convert x -> hi/lo bf16, device-scope stores (LLC-visible) ----
  {
    int gtid = bid * 256 + tid;
    if (gtid < (N * D) / 4) {
      int i = gtid * 4;
      float4 v = *(const float4*)&x[i];
      ushort4 h, lo;
      float hv;
      h.x = bf16_rne(v.x); hv = __uint_as_float((unsigned)h.x << 16); lo.x = bf16_rne(v.x - hv);
      h.y = bf16_rne(v.y); hv = __uint_as_float((unsigned)h.y << 16); lo.y = bf16_rne(v.y - hv);
      h.z = bf16_rne(v.z); hv = __uint_as_float((unsigned)h.z << 16); lo.z = bf16_rne(v.z - hv);
      h.w = bf16_rne(v.w); hv = __uint_as_float((unsigned)h.w << 16); lo.w = bf16_rne(v.w - hv);
      union { ushort4 s; unsigned long long q; } uh, ul;
      uh.s = h; ul.s = lo;
      stg8(&xh[i], uh.q);
      stg8(&xl[i], ul.q);
    }
  }
  gbar(flags, rel, 1u, tid, bid);

  // ---- tile decode: one tile per block, triangular ----
  int I = 0, rem = bid;
  while (rem >= NT - I) { rem -= NT - I; ++I; }
  int J = I + rem;
  const int i0 = I * 128, j0 = J * 128;
  const bool diag = (I == J);

  if (tid < 128) { tgI[tid] = tgt[i0 + tid]; tgJ[tid] = tgt[j0 + tid]; }

  const int l = tid & 63, wid = tid >> 6;
  const int wr = wid >> 1, wc = wid & 1;
  const int g = l >> 4, c = l & 15;

  // ---- Phase 1: GEMM with zero LDS, zero syncthreads: direct LLC fragment loads ----
  f32x4 acc[4][4];
#pragma unroll
  for (int m = 0; m < 4; ++m)
#pragma unroll
    for (int n = 0; n < 4; ++n) acc[m][n] = f32x4{0.f, 0.f, 0.f, 0.f};

  for (int kt = 0; kt < 4; ++kt) {
    const int ko = kt * 32 + g * 8;
    bf16x8 fah[4], fal[4], fbh[4], fbl[4];
#pragma unroll
    for (int m = 0; m < 4; ++m) {
      const size_t ra = (size_t)(i0 + wr * 64 + m * 16 + c) * D + ko;
      fah[m] = ldfrag(xh + ra);
      fal[m] = ldfrag(xl + ra);
    }
#pragma unroll
    for (int n = 0; n < 4; ++n) {
      const size_t rb = (size_t)(j0 + wc * 64 + n * 16 + c) * D + ko;
      fbh[n] = ldfrag(xh + rb);
      fbl[n] = ldfrag(xl + rb);
    }
#pragma unroll
    for (int n = 0; n < 4; ++n)
#pragma unroll
      for (int m = 0; m < 4; ++m) {
        acc[m][n] = __builtin_amdgcn_mfma_f32_16x16x32_bf16(fah[m], fbh[n], acc[m][n], 0, 0, 0);
        acc[m][n] = __builtin_amdgcn_mfma_f32_16x16x32_bf16(fah[m], fbl[n], acc[m][n], 0, 0, 0);
        acc[m][n] = __builtin_amdgcn_mfma_f32_16x16x32_bf16(fal[m], fbh[n], acc[m][n], 0, 0, 0);
      }
  }

  // ---- min/max epilogues + device atomics ----
  epi_minmax_I(acc, tgI, tgJ, redA, redB, minE, maxE, i0, tid);
  if (!diag)
    epi_minmax_J(acc, tgI, tgJ, redA, redB, minE, maxE, j0, tid);
  gbar(flags, rel, 2u, tid, bid);

  // ---- Phase 2: read final min/max (2 loads/row) + mining epilogue (atomicAdd) ----
  const int mode = hm[0];
  {
    const int half = tid >> 7, r = tid & 127;
    const int rowg = (half ? j0 : i0) + r;
    unsigned kmin = ldu(&minE[rowg]);
    unsigned kmax = ldu(&maxE[rowg]);
    float mn = (kmin == 0xFFFFFFFFu) ?  BIGV : dec(kmin);
    float mx = (kmax == 0u)          ? -BIGV : dec(kmax);
    if (half == 0) { rdI0[r] = mn; rdI1[r] = mx; rdI2[r] = marg[rowg]; rdI3[r] = wgt[rowg]; }
    else           { rdJ0[r] = mn; rdJ1[r] = mx; rdJ2[r] = marg[rowg]; rdJ3[r] = wgt[rowg]; }
  }
  __syncthreads();
  epi_mine_I(acc, tgI, tgJ, rdI0, rdI1, rdI2, rdI3, redA, redB, redC, redD,
             possum, negsum, apsum, ansum, i0, mode, tid);
  if (!diag)
    epi_mine_J(acc, tgI, tgJ, rdJ0, rdJ1, rdJ2, rdJ3, redA, redB, redC, redD,
               possum, negsum, apsum, ansum, j0, mode, tid);

  // ---- Phase 3: workers post flag and exit; blocks 0..15 do finals ----
  post_flag(flags, 3u, tid, bid);
  if (bid >= 16) return;

  for (;;) {
    if (flags_ready(flags, 3u, tid)) break;
    __builtin_amdgcn_s_sleep(2);
  }
  __syncthreads();

  {
    int i = bid * 256 + tid;
    float ps = ldg1(&possum[i]), ns = ldg1(&negsum[i]);
    float ap = ldg1(&apsum[i]),  an = ldg1(&ansum[i]);
    float loss_i = 1.0f * log1pf(ps) + 0.2f * log1pf(ns);
    if (mode == 1 && (ap + an) < 1.0f) { loss_i = 0.f; ap = 0.f; an = 0.f; }
    out[1 + i]     = ap;
    out[1 + N + i] = an;

    float v = loss_i;
#pragma unroll
    for (int msk = 32; msk; msk >>= 1) v += __shfl_down(v, msk, 64);
    if ((tid & 63) == 0) redA[tid >> 6] = v;
    __syncthreads();
    if (tid == 0) {
      stg(&lpart[bid], redA[0] + redA[1] + redA[2] + redA[3]);
      unsigned o = __hip_atomic_fetch_add(done, 1u, __ATOMIC_ACQ_REL, __HIP_MEMORY_SCOPE_AGENT);
      if (o == 15u) {
        float s = 0.f;
#pragma unroll
        for (int k2 = 0; k2 < 16; ++k2) s += ldg1(&lpart[k2]);
        out[0] = s / (float)N;
      }
    }
  }
}

extern "C" void kernel_launch(void* const* d_in, const int* in_sizes, int n_in,
                              void* d_out, int out_size, void* d_ws, size_t ws_size,
                              hipStream_t stream)
{
  (void)in_sizes; (void)n_in; (void)out_size; (void)ws_size;
  const float* x    = (const float*)d_in[0];
  const int*   tgt  = (const int*)d_in[1];
  const float* marg = (const float*)d_in[2];
  const float* wgt  = (const float*)d_in[3];
  const int*   hm   = (const int*)d_in[4];
  float* out = (float*)d_out;

  char* base = (char*)d_ws;
  ushort*   xh     = (ushort*)base;                  // 1 MB
  ushort*   xl     = (ushort*)(base + (1 << 20));    // 1 MB
  unsigned* minE   = (unsigned*)(base + (2 << 20));  // N keys (init 0xFF = +max)
  unsigned* maxE   = minE + N;                       // N keys (init 0x00 = -max)
  float*    possum = (float*)(maxE + N);             // N
  float*    negsum = possum + N;                     // N
  float*    apsum  = negsum + N;                     // N
  float*    ansum  = apsum + N;                      // N
  float*    lpart  = ansum + N;                      // 16
  unsigned* flags  = (unsigned*)(lpart + 16);        // NBLK
  unsigned* rel    = flags + NBLK;
  unsigned* done   = rel + 1;

  hipMemsetAsync(minE, 0xFF, N * sizeof(unsigned), stream);
  hipMemsetAsync(maxE, 0x00, 5 * N * sizeof(float), stream);   // maxE + 4 sum arrays
  hipMemsetAsync(flags, 0, (NBLK + 2) * sizeof(unsigned), stream);
  k_fused<<<NBLK, 256, 0, stream>>>(x, tgt, marg, wgt, hm, out, xh, xl,
                                    minE, maxE, possum, negsum, apsum, ansum,
                                    lpart, flags, rel, done);
}

// Round 11
// 63.388 us; speedup vs baseline: 1.6074x; 1.6074x over previous
//
#include <hip/hip_runtime.h>
#include <math.h>

#define N 4096
#define D 128
#define NT 32                 // 4096/128 tiles per dim
#define NBLK (NT*(NT+1)/2)    // 528 tiles, one block each
#define LSTR 40               // padded LDS row stride (bf16 elems), 16B-aligned rows
#define BIGV 1e30f

typedef __bf16 bf16x8 __attribute__((ext_vector_type(8)));
typedef float  f32x4  __attribute__((ext_vector_type(4)));

// ---- device-scope (LLC coherence point) accessors ----
__device__ __forceinline__ void stg(float* p, float v) {
  __hip_atomic_store(p, v, __ATOMIC_RELAXED, __HIP_MEMORY_SCOPE_AGENT);
}
__device__ __forceinline__ float ldg1(const float* p) {
  return __hip_atomic_load((float*)p, __ATOMIC_RELAXED, __HIP_MEMORY_SCOPE_AGENT);
}
__device__ __forceinline__ unsigned ldu(const unsigned* p) {
  return __hip_atomic_load((unsigned*)p, __ATOMIC_RELAXED, __HIP_MEMORY_SCOPE_AGENT);
}

// ---- monotone IEEE-754 <-> uint key (bijective; atomicMin/Max == float min/max) ----
__device__ __forceinline__ unsigned enc(float f) {
  unsigned u = __float_as_uint(f);
  return (u & 0x80000000u) ? ~u : (u | 0x80000000u);
}
__device__ __forceinline__ float dec(unsigned k) {
  unsigned u = (k & 0x80000000u) ? (k & 0x7FFFFFFFu) : ~k;
  return __uint_as_float(u);
}

// ---- flag-based device barrier over NBLK blocks (no RMW storm) ----
__device__ __forceinline__ void post_flag(unsigned* flags, unsigned ep, int tid, int bid) {
  __syncthreads();
  if (tid == 0) {
    asm volatile("s_waitcnt vmcnt(0)" ::: "memory");
    __hip_atomic_store(&flags[bid], ep, __ATOMIC_RELAXED, __HIP_MEMORY_SCOPE_AGENT);
  }
}
__device__ __forceinline__ bool flags_ready(const unsigned* flags, unsigned ep, int tid) {
  unsigned a0 = ldu(&flags[tid]);
  unsigned a1 = ldu(&flags[tid + 256]);
  bool ok = (a0 >= ep) && (a1 >= ep);
  if (tid < NBLK - 512) ok = ok && (ldu(&flags[tid + 512]) >= ep);
  return ok;
}
__device__ __forceinline__ void gbar(unsigned* flags, unsigned* rel,
                                     unsigned ep, int tid, int bid) {
  post_flag(flags, ep, tid, bid);
  if (bid == 0) {
    while (!flags_ready(flags, ep, tid)) __builtin_amdgcn_s_sleep(2);
    __syncthreads();
    if (tid == 0)
      __hip_atomic_store(rel, ep, __ATOMIC_RELAXED, __HIP_MEMORY_SCOPE_AGENT);
  }
  if (tid == 0) {
    while (ldu(rel) < ep) __builtin_amdgcn_s_sleep(4);
  }
  asm volatile("" ::: "memory");
  __syncthreads();
}

// ---- split 8 f32 -> hi(+lo) bf16, rne/rne (proven bit-exact path) ----
__device__ __forceinline__ void cvt8(float4 v0, float4 v1, int4& hp, int4& lp) {
  float vf[8] = {v0.x, v0.y, v0.z, v0.w, v1.x, v1.y, v1.z, v1.w};
  unsigned h[8], l[8];
#pragma unroll
  for (int i = 0; i < 8; ++i) {
    unsigned u = __float_as_uint(vf[i]);
    unsigned hr = (u + 0x7FFFu + ((u >> 16) & 1u)) >> 16;
    float hv = __uint_as_float(hr << 16);
    unsigned ul = __float_as_uint(vf[i] - hv);
    unsigned lr = (ul + 0x7FFFu + ((ul >> 16) & 1u)) >> 16;
    h[i] = hr; l[i] = lr;
  }
  hp = make_int4((int)(h[0] | (h[1] << 16)), (int)(h[2] | (h[3] << 16)),
                 (int)(h[4] | (h[5] << 16)), (int)(h[6] | (h[7] << 16)));
  lp = make_int4((int)(l[0] | (l[1] << 16)), (int)(l[2] | (l[3] << 16)),
                 (int)(l[4] | (l[5] << 16)), (int)(l[6] | (l[7] << 16)));
}
__device__ __forceinline__ void cvt8hi(float4 v0, float4 v1, int4& hp) {
  float vf[8] = {v0.x, v0.y, v0.z, v0.w, v1.x, v1.y, v1.z, v1.w};
  unsigned h[8];
#pragma unroll
  for (int i = 0; i < 8; ++i) {
    unsigned u = __float_as_uint(vf[i]);
    h[i] = (u + 0x7FFFu + ((u >> 16) & 1u)) >> 16;
  }
  hp = make_int4((int)(h[0] | (h[1] << 16)), (int)(h[2] | (h[3] << 16)),
                 (int)(h[4] | (h[5] << 16)), (int)(h[6] | (h[7] << 16)));
}

// Off-diag: sim = hiA*hiB + hiA*loB (2 products; |err| ~ 1.7e-4, counts shift <= ~2).
// Diag: exact 3-product (hiA*hiA + hiA*loA + loA*hiA), loA staged in Bl -- keeps the
// self-sim `s < 1.0` exclusion bit-identical to the proven R2 path.
__device__ __forceinline__ void tile_gemm(f32x4 (&acc)[4][4],
    const float* __restrict__ x, int i0, int j0, bool diagp,
    __bf16* Ah, __bf16* Bh, __bf16* Bl, int tid)
{
  const int l = tid & 63, wid = tid >> 6;
  const int wr = wid >> 1, wc = wid & 1;
  const int g = l >> 4, c = l & 15;

  for (int kt = 0; kt < 4; ++kt) {
    __syncthreads();
    {
      int r = tid >> 2, q = tid & 3;
#pragma unroll
      for (int h2 = 0; h2 < 2; ++h2) {
        int row = r + h2 * 64;
        const float* src = &x[(i0 + row) * D + kt * 32 + q * 8];
        float4 v0 = *(const float4*)src, v1 = *(const float4*)(src + 4);
        int4 hp, lp;
        if (diagp) {
          cvt8(v0, v1, hp, lp);
          *(int4*)&Ah[row * LSTR + q * 8] = hp;
          *(int4*)&Bl[row * LSTR + q * 8] = lp;
        } else {
          cvt8hi(v0, v1, hp);
          *(int4*)&Ah[row * LSTR + q * 8] = hp;
          const float* srcb = &x[(j0 + row) * D + kt * 32 + q * 8];
          float4 w0 = *(const float4*)srcb, w1 = *(const float4*)(srcb + 4);
          cvt8(w0, w1, hp, lp);
          *(int4*)&Bh[row * LSTR + q * 8] = hp;
          *(int4*)&Bl[row * LSTR + q * 8] = lp;
        }
      }
    }
    __syncthreads();

    bf16x8 fah[4], fal[4];
#pragma unroll
    for (int m = 0; m < 4; ++m) {
      int row = wr * 64 + m * 16 + c;
      fah[m] = *(const bf16x8*)&Ah[row * LSTR + g * 8];
      if (diagp) fal[m] = *(const bf16x8*)&Bl[row * LSTR + g * 8];
    }
    const __bf16* BhP = diagp ? Ah : Bh;
#pragma unroll
    for (int n = 0; n < 4; ++n) {
      int col = wc * 64 + n * 16 + c;
      bf16x8 fbh = *(const bf16x8*)&BhP[col * LSTR + g * 8];
      bf16x8 fbl = *(const bf16x8*)&Bl[col * LSTR + g * 8];
#pragma unroll
      for (int m = 0; m < 4; ++m) {
        acc[m][n] = __builtin_amdgcn_mfma_f32_16x16x32_bf16(fah[m], fbh, acc[m][n], 0, 0, 0);
        acc[m][n] = __builtin_amdgcn_mfma_f32_16x16x32_bf16(fah[m], fbl, acc[m][n], 0, 0, 0);
        if (diagp)
          acc[m][n] = __builtin_amdgcn_mfma_f32_16x16x32_bf16(fal[m], fbh, acc[m][n], 0, 0, 0);
      }
    }
  }
}

__device__ __forceinline__ void epi_minmax_I(const f32x4 (&acc)[4][4],
    const int* tgI, const int* tgJ, float* redA, float* redB,
    unsigned* __restrict__ minE, unsigned* __restrict__ maxE, int i0, int tid)
{
  const int l = tid & 63, wid = tid >> 6;
  const int wr = wid >> 1, wc = wid & 1;
  const int g = l >> 4, c = l & 15;
  int tgc[4];
#pragma unroll
  for (int n = 0; n < 4; ++n) tgc[n] = tgJ[wc * 64 + n * 16 + c];
  __syncthreads();
#pragma unroll
  for (int m = 0; m < 4; ++m)
#pragma unroll
    for (int jj = 0; jj < 4; ++jj) {
      int row_loc = wr * 64 + m * 16 + g * 4 + jj;
      int trow = tgI[row_loc];
      float mn = BIGV, mx = -BIGV;
#pragma unroll
      for (int n = 0; n < 4; ++n) {
        float s = acc[m][n][jj];
        if (trow == tgc[n]) { if (s < 1.0f) mn = fminf(mn, s); }
        else                  mx = fmaxf(mx, s);
      }
#pragma unroll
      for (int msk = 1; msk < 16; msk <<= 1) {
        mn = fminf(mn, __shfl_xor(mn, msk, 64));
        mx = fmaxf(mx, __shfl_xor(mx, msk, 64));
      }
      if (c == 0) { redA[wc * 128 + row_loc] = mn; redB[wc * 128 + row_loc] = mx; }
    }
  __syncthreads();
  if (tid < 128) {
    float mn = fminf(redA[tid], redA[128 + tid]);
    float mx = fmaxf(redB[tid], redB[128 + tid]);
    if (mn <  BIGV) atomicMin(&minE[i0 + tid], enc(mn));
    if (mx > -BIGV) atomicMax(&maxE[i0 + tid], enc(mx));
  }
}

__device__ __forceinline__ void epi_minmax_J(const f32x4 (&acc)[4][4],
    const int* tgI, const int* tgJ, float* redA, float* redB,
    unsigned* __restrict__ minE, unsigned* __restrict__ maxE, int j0, int tid)
{
  const int l = tid & 63, wid = tid >> 6;
  const int wr = wid >> 1, wc = wid & 1;
  const int g = l >> 4, c = l & 15;
  int tgc[4];
#pragma unroll
  for (int n = 0; n < 4; ++n) tgc[n] = tgJ[wc * 64 + n * 16 + c];
  __syncthreads();
  float mnn[4], mxx[4];
#pragma unroll
  for (int n = 0; n < 4; ++n) { mnn[n] = BIGV; mxx[n] = -BIGV; }
#pragma unroll
  for (int m = 0; m < 4; ++m)
#pragma unroll
    for (int jj = 0; jj < 4; ++jj) {
      int row_loc = wr * 64 + m * 16 + g * 4 + jj;
      int tcol = tgI[row_loc];
#pragma unroll
      for (int n = 0; n < 4; ++n) {
        float s = acc[m][n][jj];
        if (tgc[n] == tcol) { if (s < 1.0f) mnn[n] = fminf(mnn[n], s); }
        else                  mxx[n] = fmaxf(mxx[n], s);
      }
    }
#pragma unroll
  for (int n = 0; n < 4; ++n) {
#pragma unroll
    for (int msk = 16; msk < 64; msk <<= 1) {
      mnn[n] = fminf(mnn[n], __shfl_xor(mnn[n], msk, 64));
      mxx[n] = fmaxf(mxx[n], __shfl_xor(mxx[n], msk, 64));
    }
  }
  if (g == 0) {
#pragma unroll
    for (int n = 0; n < 4; ++n) {
      redA[wr * 128 + wc * 64 + n * 16 + c] = mnn[n];
      redB[wr * 128 + wc * 64 + n * 16 + c] = mxx[n];
    }
  }
  __syncthreads();
  if (tid < 128) {
    float mn = fminf(redA[tid], redA[128 + tid]);
    float mx = fmaxf(redB[tid], redB[128 + tid]);
    if (mn <  BIGV) atomicMin(&minE[j0 + tid], enc(mn));
    if (mx > -BIGV) atomicMax(&maxE[j0 + tid], enc(mx));
  }
}

__device__ __forceinline__ void epi_mine_I(const f32x4 (&acc)[4][4],
    const int* tgI, const int* tgJ,
    const float* rd0, const float* rd1, const float* rd2, const float* rd3,
    float* redA, float* redB, float* redC, float* redD,
    float* __restrict__ possum, float* __restrict__ negsum,
    float* __restrict__ apsum,  float* __restrict__ ansum,
    int i0, int mode, int tid)
{
  const int l = tid & 63, wid = tid >> 6;
  const int wr = wid >> 1, wc = wid & 1;
  const int g = l >> 4, c = l & 15;
  int tgc[4];
#pragma unroll
  for (int n = 0; n < 4; ++n) tgc[n] = tgJ[wc * 64 + n * 16 + c];
  __syncthreads();
#pragma unroll
  for (int m = 0; m < 4; ++m)
#pragma unroll
    for (int jj = 0; jj < 4; ++jj) {
      int row_loc = wr * 64 + m * 16 + g * 4 + jj;
      int trow = tgI[row_loc];
      float mnp = rd0[row_loc], mxn = rd1[row_loc];
      float mg  = rd2[row_loc], wt  = rd3[row_loc];
      float ps = 0.f, ns = 0.f, apv = 0.f, anv = 0.f;
#pragma unroll
      for (int n = 0; n < 4; ++n) {
        float s = acc[m][n][jj];
        bool same = (trow == tgc[n]);
        if (mode == 1) {
          float wsim = s * wt;
          if (same) {
            if (s < 1.0f && (mxn - s + mg > 0.f)) { ps += __expf(-2.f * (wsim - 0.5f)); apv += 1.f; }
          } else {
            if (s + mg - mnp > 0.f) { ns += __expf(10.f * (wsim - 0.5f)); anv += 1.f; }
          }
        } else {
          if (same) {
            if (s < 1.0f) { ps += __expf(-2.f * (s - 0.5f - mg)); apv += 1.f; }
          } else {
            ns += __expf(10.f * (s - 0.5f + mg)); anv += 1.f;
          }
        }
      }
#pragma unroll
      for (int msk = 1; msk < 16; msk <<= 1) {
        ps  += __shfl_xor(ps,  msk, 64);
        ns  += __shfl_xor(ns,  msk, 64);
        apv += __shfl_xor(apv, msk, 64);
        anv += __shfl_xor(anv, msk, 64);
      }
      if (c == 0) {
        redA[wc * 128 + row_loc] = ps;  redB[wc * 128 + row_loc] = ns;
        redC[wc * 128 + row_loc] = apv; redD[wc * 128 + row_loc] = anv;
      }
    }
  __syncthreads();
  if (tid < 128) {
    float v;
    v = redA[tid] + redA[128 + tid]; if (v != 0.f) atomicAdd(&possum[i0 + tid], v);
    v = redB[tid] + redB[128 + tid]; if (v != 0.f) atomicAdd(&negsum[i0 + tid], v);
    v = redC[tid] + redC[128 + tid]; if (v != 0.f) atomicAdd(&apsum[i0 + tid], v);
    v = redD[tid] + redD[128 + tid]; if (v != 0.f) atomicAdd(&ansum[i0 + tid], v);
  }
}

__device__ __forceinline__ void epi_mine_J(const f32x4 (&acc)[4][4],
    const int* tgI, const int* tgJ,
    const float* rd0, const float* rd1, const float* rd2, const float* rd3,
    float* redA, float* redB, float* redC, float* redD,
    float* __restrict__ possum, float* __restrict__ negsum,
    float* __restrict__ apsum,  float* __restrict__ ansum,
    int j0, int mode, int tid)
{
  const int l = tid & 63, wid = tid >> 6;
  const int wr = wid >> 1, wc = wid & 1;
  const int g = l >> 4, c = l & 15;
  int tgc[4];
#pragma unroll
  for (int n = 0; n < 4; ++n) tgc[n] = tgJ[wc * 64 + n * 16 + c];
  __syncthreads();
  float mnpJ[4], mxnJ[4], mgJ[4], wtJ[4];
#pragma unroll
  for (int n = 0; n < 4; ++n) {
    int jr = wc * 64 + n * 16 + c;
    mnpJ[n] = rd0[jr]; mxnJ[n] = rd1[jr]; mgJ[n] = rd2[jr]; wtJ[n] = rd3[jr];
  }
  float psn[4], nsn[4], apn[4], ann[4];
#pragma unroll
  for (int n = 0; n < 4; ++n) { psn[n] = 0.f; nsn[n] = 0.f; apn[n] = 0.f; ann[n] = 0.f; }
#pragma unroll
  for (int m = 0; m < 4; ++m)
#pragma unroll
    for (int jj = 0; jj < 4; ++jj) {
      int row_loc = wr * 64 + m * 16 + g * 4 + jj;
      int tcol = tgI[row_loc];
#pragma unroll
      for (int n = 0; n < 4; ++n) {
        float s = acc[m][n][jj];
        bool same = (tgc[n] == tcol);
        if (mode == 1) {
          float wsim = s * wtJ[n];
          if (same) {
            if (s < 1.0f && (mxnJ[n] - s + mgJ[n] > 0.f)) { psn[n] += __expf(-2.f * (wsim - 0.5f)); apn[n] += 1.f; }
          } else {
            if (s + mgJ[n] - mnpJ[n] > 0.f) { nsn[n] += __expf(10.f * (wsim - 0.5f)); ann[n] += 1.f; }
          }
        } else {
          if (same) {
            if (s < 1.0f) { psn[n] += __expf(-2.f * (s - 0.5f - mgJ[n])); apn[n] += 1.f; }
          } else {
            nsn[n] += __expf(10.f * (s - 0.5f + mgJ[n])); ann[n] += 1.f;
          }
        }
      }
    }
#pragma unroll
  for (int n = 0; n < 4; ++n) {
#pragma unroll
    for (int msk = 16; msk < 64; msk <<= 1) {
      psn[n] += __shfl_xor(psn[n], msk, 64);
      nsn[n] += __shfl_xor(nsn[n], msk, 64);
      apn[n] += __shfl_xor(apn[n], msk, 64);
      ann[n] += __shfl_xor(ann[n], msk, 64);
    }
  }
  if (g == 0) {
#pragma unroll
    for (int n = 0; n < 4; ++n) {
      int col_loc = wc * 64 + n * 16 + c;
      redA[wr * 128 + col_loc] = psn[n]; redB[wr * 128 + col_loc] = nsn[n];
      redC[wr * 128 + col_loc] = apn[n]; redD[wr * 128 + col_loc] = ann[n];
    }
  }
  __syncthreads();
  if (tid < 128) {
    float v;
    v = redA[tid] + redA[128 + tid]; if (v != 0.f) atomicAdd(&possum[j0 + tid], v);
    v = redB[tid] + redB[128 + tid]; if (v != 0.f) atomicAdd(&negsum[j0 + tid], v);
    v = redC[tid] + redC[128 + tid]; if (v != 0.f) atomicAdd(&apsum[j0 + tid], v);
    v = redD[tid] + redD[128 + tid]; if (v != 0.f) atomicAdd(&ansum[j0 + tid], v);
  }
}

__global__ __launch_bounds__(256, 2)
void k_fused(const float* __restrict__ x, const int* __restrict__ tgt,
             const float* __restrict__ marg, const float* __restrict__ wgt,
             const int* __restrict__ hm, float* __restrict__ out,
             unsigned* __restrict__ minE, unsigned* __restrict__ maxE,
             float* __restrict__ possum, float* __restrict__ negsum,
             float* __restrict__ apsum,  float* __restrict__ ansum,
             float* __restrict__ lpart, unsigned* flags, unsigned* rel,
             unsigned* done)
{
  __shared__ __bf16 Ah[128*LSTR], Bh[128*LSTR], Bl[128*LSTR];   // 30720 B
  __shared__ int tgI[128], tgJ[128];
  __shared__ float rdI0[128], rdI1[128], rdI2[128], rdI3[128];
  __shared__ float rdJ0[128], rdJ1[128], rdJ2[128], rdJ3[128];
  __shared__ float redA[256], redB[256], redC[256], redD[256];

  const int tid = threadIdx.x;
  const int bid = blockIdx.x;

  // ---- tile decode: one tile per block, triangular ----
  int I = 0, rem = bid;
  while (rem >= NT - I) { rem -= NT - I; ++I; }
  int J = I + rem;
  const int i0 = I * 128, j0 = J * 128;
  const bool diag = (I == J);

  if (tid < 128) { tgI[tid] = tgt[i0 + tid]; tgJ[tid] = tgt[j0 + tid]; }

  f32x4 acc[4][4];
#pragma unroll
  for (int m = 0; m < 4; ++m)
#pragma unroll
    for (int n = 0; n < 4; ++n) acc[m][n] = f32x4{0.f, 0.f, 0.f, 0.f};

  // ---- Phase 1: GEMM (inline hi/lo convert; race-free) + min/max atomics ----
  tile_gemm(acc, x, i0, j0, diag, Ah, Bh, Bl, tid);
  epi_minmax_I(acc, tgI, tgJ, redA, redB, minE, maxE, i0, tid);
  if (!diag)
    epi_minmax_J(acc, tgI, tgJ, redA, redB, minE, maxE, j0, tid);
  gbar(flags, rel, 1u, tid, bid);

  // ---- Phase 2: read final min/max (2 loads/row) + mining epilogue (atomicAdd) ----
  const int mode = hm[0];
  {
    const int half = tid >> 7, r = tid & 127;
    const int rowg = (half ? j0 : i0) + r;
    unsigned kmin = ldu(&minE[rowg]);
    unsigned kmax = ldu(&maxE[rowg]);
    float mn = (kmin == 0xFFFFFFFFu) ?  BIGV : dec(kmin);
    float mx = (kmax == 0u)          ? -BIGV : dec(kmax);
    if (half == 0) { rdI0[r] = mn; rdI1[r] = mx; rdI2[r] = marg[rowg]; rdI3[r] = wgt[rowg]; }
    else           { rdJ0[r] = mn; rdJ1[r] = mx; rdJ2[r] = marg[rowg]; rdJ3[r] = wgt[rowg]; }
  }
  __syncthreads();
  epi_mine_I(acc, tgI, tgJ, rdI0, rdI1, rdI2, rdI3, redA, redB, redC, redD,
             possum, negsum, apsum, ansum, i0, mode, tid);
  if (!diag)
    epi_mine_J(acc, tgI, tgJ, rdJ0, rdJ1, rdJ2, rdJ3, redA, redB, redC, redD,
               possum, negsum, apsum, ansum, j0, mode, tid);

  // ---- Phase 3: workers post flag and exit; blocks 0..15 do finals ----
  post_flag(flags, 2u, tid, bid);
  if (bid >= 16) return;

  for (;;) {
    if (flags_ready(flags, 2u, tid)) break;
    __builtin_amdgcn_s_sleep(2);
  }
  __syncthreads();

  {
    int i = bid * 256 + tid;
    float ps = ldg1(&possum[i]), ns = ldg1(&negsum[i]);
    float ap = ldg1(&apsum[i]),  an = ldg1(&ansum[i]);
    float loss_i = 1.0f * log1pf(ps) + 0.2f * log1pf(ns);
    if (mode == 1 && (ap + an) < 1.0f) { loss_i = 0.f; ap = 0.f; an = 0.f; }
    out[1 + i]     = ap;
    out[1 + N + i] = an;

    float v = loss_i;
#pragma unroll
    for (int msk = 32; msk; msk >>= 1) v += __shfl_down(v, msk, 64);
    if ((tid & 63) == 0) redA[tid >> 6] = v;
    __syncthreads();
    if (tid == 0) {
      stg(&lpart[bid], redA[0] + redA[1] + redA[2] + redA[3]);
      unsigned o = __hip_atomic_fetch_add(done, 1u, __ATOMIC_ACQ_REL, __HIP_MEMORY_SCOPE_AGENT);
      if (o == 15u) {
        float s = 0.f;
#pragma unroll
        for (int k2 = 0; k2 < 16; ++k2) s += ldg1(&lpart[k2]);
        out[0] = s / (float)N;
      }
    }
  }
}

extern "C" void kernel_launch(void* const* d_in, const int* in_sizes, int n_in,
                              void* d_out, int out_size, void* d_ws, size_t ws_size,
                              hipStream_t stream)
{
  (void)in_sizes; (void)n_in; (void)out_size; (void)ws_size;
  const float* x    = (const float*)d_in[0];
  const int*   tgt  = (const int*)d_in[1];
  const float* marg = (const float*)d_in[2];
  const float* wgt  = (const float*)d_in[3];
  const int*   hm   = (const int*)d_in[4];
  float* out = (float*)d_out;

  // workspace layout: minE (0xFF-init), then one contiguous zero-init region
  unsigned* minE   = (unsigned*)d_ws;          // N keys, init 0xFF (= +max key)
  unsigned* maxE   = minE + N;                 // N keys, init 0x00 (= -max key)
  float*    possum = (float*)(maxE + N);       // N
  float*    negsum = possum + N;               // N
  float*    apsum  = negsum + N;               // N
  float*    ansum  = apsum + N;                // N
  float*    lpart  = ansum + N;                // 16
  unsigned* flags  = (unsigned*)(lpart + 16);  // NBLK
  unsigned* rel    = flags + NBLK;             // 1
  unsigned* done   = rel + 1;                  // 1

  hipMemsetAsync(minE, 0xFF, N * sizeof(unsigned), stream);
  hipMemsetAsync(maxE, 0x00, (5 * N + 16 + NBLK + 2) * sizeof(unsigned), stream);
  k_fused<<<NBLK, 256, 0, stream>>>(x, tgt, marg, wgt, hm, out,
                                    minE, maxE, possum, negsum, apsum, ansum,
                                    lpart, flags, rel, done);
}